// Round 14
// baseline (930.085 us; speedup 1.0000x reference)
//
#include <hip/hip_runtime.h>
#include <hip/hip_bf16.h>
#include <math.h>

#define NTOK 8192
#define HD   1024
#define FFND 2048
#define NE   64
#define MTOT 16384   // NTOK * TOPK
#define PER_E 256    // MTOT / NE

typedef __attribute__((ext_vector_type(8))) short bh8;
typedef __attribute__((ext_vector_type(4))) float f4;
typedef unsigned short u16;
typedef unsigned int   u32;

#define SB0 __builtin_amdgcn_sched_barrier(0)

__device__ __forceinline__ u16 f2bf(float f) {
  union { float f; u32 u; } x; x.f = f;
  u32 r = x.u + 0x7fffu + ((x.u >> 16) & 1u);   // round-nearest-even
  return (u16)(r >> 16);
}

__device__ __forceinline__ float bf2f(u16 b) {
  union { u32 u; float f; } x; x.u = ((u32)b) << 16; return x.f;
}

__device__ __forceinline__ u32 pk2(float lo, float hi) {
  __hip_bfloat162 h = __float22bfloat162_rn(make_float2(lo, hi));
  union { __hip_bfloat162 h; u32 u; } c; c.h = h;
  return c.u;
}

// slot -> source token map. scatter_index flat: sidx[t*2+k] = slot.
__global__ void k_build_s2t(const int* __restrict__ sidx, int* __restrict__ s2t) {
  int i = blockIdx.x * 256 + threadIdx.x;   // i in [0, MTOT)
  s2t[sidx[i]] = i >> 1;
}

// Gather + f32->bf16 convert: X[slot][h] = bf16(inputs[s2t[slot]][h])
__global__ void k_gather_x(const float* __restrict__ inp, const int* __restrict__ s2t,
                           u16* __restrict__ X) {
  int idx = blockIdx.x * 256 + threadIdx.x;   // MTOT*HD/8 threads
  int slot = idx >> 7;                        // HD/8 = 128 chunks per row
  int c    = idx & 127;
  const float* src = inp + (size_t)s2t[slot] * HD + c * 8;
  float v[8];
  *(f4*)(v)     = *(const f4*)(src);
  *(f4*)(v + 4) = *(const f4*)(src + 4);
  u32 o[4];
  #pragma unroll
  for (int j = 0; j < 4; ++j) o[j] = pk2(v[2 * j], v[2 * j + 1]);
  *(uint4*)(X + (size_t)slot * HD + c * 8) = *(uint4*)o;
}

// Grouped GEMM, BM=BN=256, single-barrier K-loop:
//   As dbuf (2x32KB, global_load_lds) + Bs dbuf (2x32KB) + breg dbuf (depth-2).
//   iter t: issue loadB(t+2)->breg[t&1], stageA(t+1)->As[cur^1];
//           vmcnt(36) retires B(t+1)+A(t) (each issued a FULL K-step earlier);
//           writeB(t+1)->Bs[cur^1] (interleaves with MFMA, no fence);
//           MFMA(t) on As[cur]/Bs[cur]; lgkmcnt(0); ONE s_barrier.
template<int K, int N, bool GELU>
__global__ __launch_bounds__(512, 2)
void moe_gemm(const u16* __restrict__ Abf, const float* __restrict__ Bf,
              u16* __restrict__ outp)
{
  constexpr int BM = 256, BN = 256, BK = 64;
  constexpr int NB = N / BN;                  // n0-blocks per expert
  constexpr int NT = K / BK;                  // K-steps (>= 3)
  constexpr int NF = 8;                       // b-fragments per wave
  constexpr int BITER = 4;                    // B staging chunk-iters
  constexpr int ABYTES = BM * 128;            // 32 KB
  constexpr int BBYTES = BN * 128;            // 32 KB
  __shared__ __align__(16) char lds[2 * ABYTES + 2 * BBYTES];   // 128 KB

  // XCD swizzle, n0 innermost.
  const int d = blockIdx.y * NB + blockIdx.x;
  const int x = d & 7, j = d >> 3;
  const int e  = x * (NE / 8) + j / NB;
  const int n0 = (j % NB) * BN;
  const int row0 = e * PER_E;
  const int tid  = threadIdx.x;
  const int lane = tid & 63, wid = tid >> 6;
  const int wr   = wid >> 1, wc = wid & 1;    // 4x2 waves: 64 x 128 each

  const u16*   Arow = Abf + (size_t)row0 * K;
  const float* Bsrc = Bf + (size_t)e * K * N + n0;

  auto stageA = [&](int buf, int k0) {
    char* dst = lds + buf * ABYTES;
    #pragma unroll
    for (int i = 0; i < 4; ++i) {
      int c = i * 512 + tid;
      int r = c >> 3, kc = c & 7;
      int kswz = kc ^ (r & 7);
      __builtin_amdgcn_global_load_lds(
          (const void*)(Arow + (size_t)r * K + k0 + kswz * 8),
          (void*)(dst + c * 16), 16, 0, 0);
    }
  };
  auto loadB = [&](float* br, int k0) {
    #pragma unroll
    for (int i = 0; i < BITER; ++i) {
      int c = i * 512 + tid;
      int n = c & (BN - 1), kc = c / BN;      // kc 0..7
      const float* p = Bsrc + (size_t)(k0 + kc * 8) * N + n;
      #pragma unroll
      for (int jj = 0; jj < 8; ++jj) br[i * 8 + jj] = p[(size_t)jj * N];
    }
  };
  auto writeB = [&](int buf, const float* br) {
    char* dst = lds + 2 * ABYTES + buf * BBYTES;
    #pragma unroll
    for (int i = 0; i < BITER; ++i) {
      int c = i * 512 + tid;
      int n = c & (BN - 1), kc = c / BN;
      u32 q[4];
      #pragma unroll
      for (int jj = 0; jj < 4; ++jj) q[jj] = pk2(br[i * 8 + 2 * jj], br[i * 8 + 2 * jj + 1]);
      *(uint4*)(dst + n * 128 + ((kc * 16) ^ ((n & 7) << 4))) = *(uint4*)q;
    }
  };

  f4 acc[4][NF] = {};
  float breg0[BITER * 8], breg1[BITER * 8];

  // ---- prologue: B(0),A(0),B(1) in flight; write Bs[0]; one barrier ----
  loadB(breg0, 0); SB0;
  stageA(0, 0); SB0;
  loadB(breg1, BK); SB0;
  asm volatile("s_waitcnt vmcnt(36)" ::: "memory");   // retire B(0)
  SB0;
  writeB(0, breg0);
  asm volatile("s_waitcnt lgkmcnt(0)" ::: "memory");
  SB0;
  __builtin_amdgcn_s_barrier();
  SB0;

  for (int t = 0; t < NT; ++t) {
    const int cur = t & 1;
    const char* As = lds + cur * ABYTES;
    const char* Bs = lds + 2 * ABYTES + cur * BBYTES;
    // ---- issue next loads ----
    if (t + 2 < NT) { loadB((t & 1) ? breg1 : breg0, (t + 2) * BK); SB0; }
    if (t + 1 < NT) { stageA(cur ^ 1, (t + 1) * BK); SB0; }
    // ---- single counted wait: B(t+1) and A(t), both 1 K-step old ----
    if (t + 2 < NT)      asm volatile("s_waitcnt vmcnt(36)" ::: "memory");
    else if (t + 1 < NT) asm volatile("s_waitcnt vmcnt(4)"  ::: "memory");
    else                 asm volatile("s_waitcnt vmcnt(0)"  ::: "memory");
    SB0;
    // ---- publish B(t+1) (no fence after: may interleave with MFMA) ----
    if (t + 1 < NT) writeB(cur ^ 1, ((t + 1) & 1) ? breg1 : breg0);
    // ---- MFMA(t) ----
    __builtin_amdgcn_s_setprio(1);
    #pragma unroll
    for (int kk = 0; kk < 2; ++kk) {
      int kByte = kk * 64 + ((lane >> 4) << 4);
      bh8 a[4], b[NF];
      #pragma unroll
      for (int m = 0; m < 4; ++m) {
        int r = wr * 64 + m * 16 + (lane & 15);
        a[m] = *(const bh8*)(As + r * 128 + (kByte ^ ((r & 7) << 4)));
      }
      #pragma unroll
      for (int n = 0; n < NF; ++n) {
        int r = wc * 128 + n * 16 + (lane & 15);
        b[n] = *(const bh8*)(Bs + r * 128 + (kByte ^ ((r & 7) << 4)));
      }
      #pragma unroll
      for (int m = 0; m < 4; ++m)
        #pragma unroll
        for (int n = 0; n < NF; ++n)
          acc[m][n] = __builtin_amdgcn_mfma_f32_16x16x32_bf16(a[m], b[n], acc[m][n], 0, 0, 0);
    }
    __builtin_amdgcn_s_setprio(0);
    // ---- one barrier per K-step ----
    asm volatile("s_waitcnt lgkmcnt(0)" ::: "memory");
    SB0;
    __builtin_amdgcn_s_barrier();
    SB0;
  }

  // ---- epilogue: C layout (m89) col = lane&15, row = (lane>>4)*4 + j ----
  #pragma unroll
  for (int m = 0; m < 4; ++m) {
    #pragma unroll
    for (int n = 0; n < NF; ++n) {
      int rowb = wr * 64 + m * 16 + ((lane >> 4) << 2);
      int col  = n0 + wc * 128 + n * 16 + (lane & 15);
      #pragma unroll
      for (int jj = 0; jj < 4; ++jj) {
        float xv = acc[m][n][jj];
        if (GELU) {
          float y = fminf(fmaxf(xv, -8.f), 8.f);
          float u = 0.7978845608f * (y + 0.044715f * y * y * y);
          float t2 = __expf(-2.f * u);
          float g = __fdividef(y, 1.f + t2);
          outp[(size_t)(row0 + rowb + jj) * N + col] = f2bf(g);
        } else {
          outp[(size_t)(row0 + rowb + jj) * N + col] = f2bf(xv);
        }
      }
    }
  }
}

// out[t][:] = h2[sidx[2t]][:] + h2[sidx[2t+1]][:]   (h2 bf16; out f32)
__global__ void k_reduce(const u16* __restrict__ h2, const int* __restrict__ sidx,
                         float* __restrict__ out) {
  int t = blockIdx.x;
  int c = threadIdx.x;                        // 256 threads x 4 floats = 1024
  const u16* r0 = h2 + (size_t)sidx[2 * t] * HD + c * 4;
  const u16* r1 = h2 + (size_t)sidx[2 * t + 1] * HD + c * 4;
  u16 a0[4], a1[4];
  *(uint2*)a0 = *(const uint2*)r0;
  *(uint2*)a1 = *(const uint2*)r1;
  f4 s;
  #pragma unroll
  for (int jj = 0; jj < 4; ++jj) s[jj] = bf2f(a0[jj]) + bf2f(a1[jj]);
  *(f4*)(out + (size_t)t * HD + c * 4) = s;
}

extern "C" void kernel_launch(void* const* d_in, const int* in_sizes, int n_in,
                              void* d_out, int out_size, void* d_ws, size_t ws_size,
                              hipStream_t stream) {
  const float* inp  = (const float*)d_in[0];
  const float* w1   = (const float*)d_in[1];
  const float* w2   = (const float*)d_in[2];
  const int*   sidx = (const int*)d_in[3];
  float* out = (float*)d_out;

  char* ws   = (char*)d_ws;
  int*   s2t = (int*)ws;                                          // 64 KB
  u16*   X   = (u16*)(ws + (1 << 20));                            // 32 MB bf16 [MTOT][HD]
  u16*   act = (u16*)(ws + (1 << 20) + (32u << 20));              // 64 MB bf16 [MTOT][FFND]
  u16*   h2  = (u16*)(ws + (1 << 20) + (96u << 20));              // 32 MB bf16 [MTOT][HD]

  k_build_s2t<<<MTOT / 256, 256, 0, stream>>>(sidx, s2t);
  k_gather_x<<<(MTOT * (HD / 8)) / 256, 256, 0, stream>>>(inp, s2t, X);
  moe_gemm<HD, FFND, true><<<dim3(FFND / 256, NE), 512, 0, stream>>>(X, w1, act);
  moe_gemm<FFND, HD, false><<<dim3(HD / 256, NE), 512, 0, stream>>>(act, w2, h2);
  k_reduce<<<NTOK, 256, 0, stream>>>(h2, sidx, out);
}

// Round 15
// 294.774 us; speedup vs baseline: 3.1552x; 3.1552x over previous
//
#include <hip/hip_runtime.h>
#include <hip/hip_bf16.h>
#include <math.h>

#define NTOK 8192
#define HD   1024
#define FFND 2048
#define NE   64
#define MTOT 16384   // NTOK * TOPK
#define PER_E 256    // MTOT / NE

typedef __attribute__((ext_vector_type(8))) short bh8;
typedef __attribute__((ext_vector_type(4))) float f4;
typedef unsigned short u16;
typedef unsigned int   u32;

__device__ __forceinline__ u16 f2bf(float f) {
  union { float f; u32 u; } x; x.f = f;
  u32 r = x.u + 0x7fffu + ((x.u >> 16) & 1u);   // round-nearest-even
  return (u16)(r >> 16);
}

__device__ __forceinline__ float bf2f(u16 b) {
  union { u32 u; float f; } x; x.u = ((u32)b) << 16; return x.f;
}

__device__ __forceinline__ u32 pk2(float lo, float hi) {
  __hip_bfloat162 h = __float22bfloat162_rn(make_float2(lo, hi));
  union { __hip_bfloat162 h; u32 u; } c; c.h = h;
  return c.u;
}

// slot -> source token map. scatter_index flat: sidx[t*2+k] = slot.
__global__ void k_build_s2t(const int* __restrict__ sidx, int* __restrict__ s2t) {
  int i = blockIdx.x * 256 + threadIdx.x;   // i in [0, MTOT)
  s2t[sidx[i]] = i >> 1;
}

// Gather + f32->bf16 convert: X[slot][h] = bf16(inputs[s2t[slot]][h])
__global__ void k_gather_x(const float* __restrict__ inp, const int* __restrict__ s2t,
                           u16* __restrict__ X) {
  for (int idx = blockIdx.x * 256 + threadIdx.x; idx < MTOT * (HD / 8);
       idx += 2048 * 256) {
    int slot = idx >> 7;                      // HD/8 = 128 chunks per row
    int c    = idx & 127;
    const float* src = inp + (size_t)s2t[slot] * HD + c * 8;
    float v[8];
    *(f4*)(v)     = *(const f4*)(src);
    *(f4*)(v + 4) = *(const f4*)(src + 4);
    u32 o[4];
    #pragma unroll
    for (int j = 0; j < 4; ++j) o[j] = pk2(v[2 * j], v[2 * j + 1]);
    *(uint4*)(X + (size_t)slot * HD + c * 8) = *(uint4*)o;
  }
}

// Grouped GEMM, BM=BN=256 (weights read once), 512 thr (4x2 waves, 64x128 each),
// 96 KB LDS, depth-1 prefetch with COUNTED vmcnt (round-9 pipeline, proven).
// NEW: LDS-bounce epilogue — fragments staged to a 64x256 bf16 LDS tile per
// m-chunk, then coalesced 16B stores (512B per 32 lanes) instead of scattered
// 2B stores (fixes the 32B-segment write amplification seen in WRITE_SIZE).
template<int K, int N, bool GELU>
__global__ __launch_bounds__(512, 2)
void moe_gemm(const u16* __restrict__ Abf, const float* __restrict__ Bf,
              u16* __restrict__ outp)
{
  constexpr int BM = 256, BN = 256, BK = 64;
  constexpr int NB = N / BN;                  // n0-blocks per expert
  constexpr int NT = K / BK;                  // K-steps
  constexpr int NF = 8;                       // b-fragments per wave
  constexpr int BITER = 4;                    // B staging chunk-iters
  constexpr int ABYTES = BM * 128;            // one As buffer (32 KB)
  __shared__ __align__(16) char lds[2 * ABYTES + BN * 128];  // 96 KB
  char* Bs = lds + 2 * ABYTES;     // Bs[n]: 64 bf16 (k-contig), chunk XOR (n&7)

  // XCD swizzle, n0 innermost: co-resident blocks on an XCD share A panels.
  const int d = blockIdx.y * NB + blockIdx.x;
  const int x = d & 7, j = d >> 3;
  const int e  = x * (NE / 8) + j / NB;
  const int n0 = (j % NB) * BN;
  const int row0 = e * PER_E;
  const int tid  = threadIdx.x;
  const int lane = tid & 63, wid = tid >> 6;
  const int wr   = wid >> 1, wc = wid & 1;    // 4x2 waves: 64 x 128 each

  const u16*   Arow = Abf + (size_t)row0 * K;
  const float* Bsrc = Bf + (size_t)e * K * N + n0;

  auto stageA = [&](int buf, int k0) {
    char* dst = lds + buf * ABYTES;
    #pragma unroll
    for (int i = 0; i < 4; ++i) {
      int c = i * 512 + tid;
      int r = c >> 3, kc = c & 7;
      int kswz = kc ^ (r & 7);
      __builtin_amdgcn_global_load_lds(
          (const void*)(Arow + (size_t)r * K + k0 + kswz * 8),
          (void*)(dst + c * 16), 16, 0, 0);
    }
  };
  auto loadB = [&](float* br, int k0) {
    #pragma unroll
    for (int i = 0; i < BITER; ++i) {
      int c = i * 512 + tid;
      int n = c & (BN - 1), kc = c / BN;      // kc 0..7
      const float* p = Bsrc + (size_t)(k0 + kc * 8) * N + n;
      #pragma unroll
      for (int jj = 0; jj < 8; ++jj) br[i * 8 + jj] = p[(size_t)jj * N];
    }
  };
  auto writeB = [&](const float* br) {
    #pragma unroll
    for (int i = 0; i < BITER; ++i) {
      int c = i * 512 + tid;
      int n = c & (BN - 1), kc = c / BN;
      u32 q[4];
      #pragma unroll
      for (int jj = 0; jj < 4; ++jj) q[jj] = pk2(br[i * 8 + 2 * jj], br[i * 8 + 2 * jj + 1]);
      *(uint4*)(Bs + n * 128 + ((kc * 16) ^ ((n & 7) << 4))) = *(uint4*)q;
    }
  };

  f4 acc[4][NF] = {};
  float breg[BITER * 8];

  // ---- prologue ----
  loadB(breg, 0);
  __builtin_amdgcn_sched_barrier(0);
  stageA(0, 0);
  asm volatile("s_waitcnt vmcnt(4)" ::: "memory");   // B(0) regs ready; A(0) flies
  __builtin_amdgcn_sched_barrier(0);
  writeB(breg);
  asm volatile("s_waitcnt lgkmcnt(0)" ::: "memory");
  __builtin_amdgcn_sched_barrier(0);
  __builtin_amdgcn_s_barrier();
  __builtin_amdgcn_sched_barrier(0);

  int cur = 0;
  for (int t = 0; t < NT; ++t) {
    const char* As = lds + cur * ABYTES;
    if (t + 1 < NT) {
      loadB(breg, (t + 1) * BK);
      __builtin_amdgcn_sched_barrier(0);
      stageA(cur ^ 1, (t + 1) * BK);
      asm volatile("s_waitcnt vmcnt(36)" ::: "memory");  // A(t) landed; 36 fly
    } else {
      asm volatile("s_waitcnt vmcnt(0)" ::: "memory");
    }
    __builtin_amdgcn_sched_barrier(0);
    __builtin_amdgcn_s_setprio(1);
    #pragma unroll
    for (int kk = 0; kk < 2; ++kk) {
      int kByte = kk * 64 + ((lane >> 4) << 4);
      bh8 a[4], b[NF];
      #pragma unroll
      for (int m = 0; m < 4; ++m) {
        int r = wr * 64 + m * 16 + (lane & 15);
        a[m] = *(const bh8*)(As + r * 128 + (kByte ^ ((r & 7) << 4)));
      }
      #pragma unroll
      for (int n = 0; n < NF; ++n) {
        int r = wc * 128 + n * 16 + (lane & 15);
        b[n] = *(const bh8*)(Bs + r * 128 + (kByte ^ ((r & 7) << 4)));
      }
      #pragma unroll
      for (int m = 0; m < 4; ++m)
        #pragma unroll
        for (int n = 0; n < NF; ++n)
          acc[m][n] = __builtin_amdgcn_mfma_f32_16x16x32_bf16(a[m], b[n], acc[m][n], 0, 0, 0);
    }
    __builtin_amdgcn_s_setprio(0);
    __builtin_amdgcn_s_barrier();          // done reading Bs
    __builtin_amdgcn_sched_barrier(0);
    if (t + 1 < NT) {
      asm volatile("s_waitcnt vmcnt(2)" ::: "memory");   // B(t+1) regs ready
      __builtin_amdgcn_sched_barrier(0);
      writeB(breg);
      asm volatile("s_waitcnt lgkmcnt(0)" ::: "memory");
      __builtin_amdgcn_sched_barrier(0);
      __builtin_amdgcn_s_barrier();        // Bs(t+1) published; A(t+1) in flight
      __builtin_amdgcn_sched_barrier(0);
      cur ^= 1;
    }
  }

  // ---- epilogue: LDS-bounce for coalesced stores ----
  // Per m-chunk: stage 64 rows (16 per wr-band) x 256 cols bf16 = 32 KB into T
  // (reuses Bs region), then 4 coalesced passes: 32 threads cover a full
  // 512 B row with uint4 stores.
  u16* T = (u16*)(lds + 2 * ABYTES);
  #pragma unroll
  for (int m = 0; m < 4; ++m) {
    __syncthreads();                     // previous pass done reading T
    #pragma unroll
    for (int n = 0; n < NF; ++n) {
      int tr = wr * 16 + ((lane >> 4) << 2);       // tile row base (j adds 0..3)
      int tc = wc * 128 + n * 16 + (lane & 15);    // tile col
      #pragma unroll
      for (int jj = 0; jj < 4; ++jj) {
        float xv = acc[m][n][jj];
        float g;
        if (GELU) {
          float y = fminf(fmaxf(xv, -8.f), 8.f);
          float u = 0.7978845608f * (y + 0.044715f * y * y * y);
          float t2 = __expf(-2.f * u);
          g = __fdividef(y, 1.f + t2);
        } else {
          g = xv;
        }
        T[(tr + jj) * 256 + tc] = f2bf(g);
      }
    }
    __syncthreads();                     // T filled
    #pragma unroll
    for (int u = 0; u < 4; ++u) {        // u = wr-band
      int t16 = tid >> 5;                // row within band, 0..15
      int cb  = (tid & 31) * 16;         // byte col, 0..496
      uint4 v = *(const uint4*)((const char*)T + (u * 16 + t16) * 512 + cb);
      int grow = row0 + u * 64 + m * 16 + t16;
      *(uint4*)((char*)outp + ((size_t)grow * N + n0) * 2 + cb) = v;
    }
  }
}

// out[t][:] = h2[sidx[2t]][:] + h2[sidx[2t+1]][:]   (h2 bf16; out f32)
__global__ void k_reduce(const u16* __restrict__ h2, const int* __restrict__ sidx,
                         float* __restrict__ out) {
  for (int i = blockIdx.x * 256 + threadIdx.x; i < NTOK * (HD / 4);
       i += 2048 * 256) {
    int t = i >> 8, c = i & 255;
    const u16* r0 = h2 + (size_t)sidx[2 * t] * HD + c * 4;
    const u16* r1 = h2 + (size_t)sidx[2 * t + 1] * HD + c * 4;
    u16 a0[4], a1[4];
    *(uint2*)a0 = *(const uint2*)r0;
    *(uint2*)a1 = *(const uint2*)r1;
    f4 s;
    #pragma unroll
    for (int jj = 0; jj < 4; ++jj) s[jj] = bf2f(a0[jj]) + bf2f(a1[jj]);
    *(f4*)(out + (size_t)t * HD + c * 4) = s;
  }
}

extern "C" void kernel_launch(void* const* d_in, const int* in_sizes, int n_in,
                              void* d_out, int out_size, void* d_ws, size_t ws_size,
                              hipStream_t stream) {
  const float* inp  = (const float*)d_in[0];
  const float* w1   = (const float*)d_in[1];
  const float* w2   = (const float*)d_in[2];
  const int*   sidx = (const int*)d_in[3];
  float* out = (float*)d_out;

  char* ws   = (char*)d_ws;
  int*   s2t = (int*)ws;                                          // 64 KB
  u16*   X   = (u16*)(ws + (1 << 20));                            // 32 MB bf16 [MTOT][HD]
  u16*   act = (u16*)(ws + (1 << 20) + (32u << 20));              // 64 MB bf16 [MTOT][FFND]
  u16*   h2  = (u16*)(ws + (1 << 20) + (96u << 20));              // 32 MB bf16 [MTOT][HD]

  k_build_s2t<<<MTOT / 256, 256, 0, stream>>>(sidx, s2t);
  k_gather_x<<<2048, 256, 0, stream>>>(inp, s2t, X);
  moe_gemm<HD, FFND, true><<<dim3(FFND / 256, NE), 512, 0, stream>>>(X, w1, act);
  moe_gemm<FFND, HD, false><<<dim3(HD / 256, NE), 512, 0, stream>>>(act, w2, h2);
  k_reduce<<<2048, 256, 0, stream>>>(h2, sidx, out);
}

// Round 16
// 285.580 us; speedup vs baseline: 3.2568x; 1.0322x over previous
//
#include <hip/hip_runtime.h>
#include <hip/hip_bf16.h>
#include <math.h>

#define NTOK 8192
#define HD   1024
#define FFND 2048
#define NE   64
#define MTOT 16384   // NTOK * TOPK
#define PER_E 256    // MTOT / NE

typedef __attribute__((ext_vector_type(8))) short bh8;
typedef __attribute__((ext_vector_type(4))) float f4;
typedef unsigned short u16;
typedef unsigned int   u32;

__device__ __forceinline__ u16 f2bf(float f) {
  union { float f; u32 u; } x; x.f = f;
  u32 r = x.u + 0x7fffu + ((x.u >> 16) & 1u);   // round-nearest-even
  return (u16)(r >> 16);
}

__device__ __forceinline__ float bf2f(u16 b) {
  union { u32 u; float f; } x; x.u = ((u32)b) << 16; return x.f;
}

__device__ __forceinline__ u32 pk2(float lo, float hi) {
  __hip_bfloat162 h = __float22bfloat162_rn(make_float2(lo, hi));
  union { __hip_bfloat162 h; u32 u; } c; c.h = h;
  return c.u;
}

// slot -> source token map. scatter_index flat: sidx[t*2+k] = slot.
__global__ void k_build_s2t(const int* __restrict__ sidx, int* __restrict__ s2t) {
  int i = blockIdx.x * 256 + threadIdx.x;   // i in [0, MTOT)
  s2t[sidx[i]] = i >> 1;
}

// Gather + f32->bf16 convert: X[slot][h] = bf16(inputs[s2t[slot]][h])
__global__ void k_gather_x(const float* __restrict__ inp, const int* __restrict__ s2t,
                           u16* __restrict__ X) {
  for (int idx = blockIdx.x * 256 + threadIdx.x; idx < MTOT * (HD / 8);
       idx += 2048 * 256) {
    int slot = idx >> 7;                      // HD/8 = 128 chunks per row
    int c    = idx & 127;
    const float* src = inp + (size_t)s2t[slot] * HD + c * 8;
    float v[8];
    *(f4*)(v)     = *(const f4*)(src);
    *(f4*)(v + 4) = *(const f4*)(src + 4);
    u32 o[4];
    #pragma unroll
    for (int j = 0; j < 4; ++j) o[j] = pk2(v[2 * j], v[2 * j + 1]);
    *(uint4*)(X + (size_t)slot * HD + c * 8) = *(uint4*)o;
  }
}

// Grouped GEMM, BM=BN=256 (weights read once), 512 thr (4x2 waves, 64x128 each),
// 96 KB LDS, depth-1 prefetch with COUNTED vmcnt (round-9 pipeline).
// NEW: B loaded with dwordx4 (16B/lane, 1024B/wave contiguous granule) instead
// of dword (4B/lane, 256B granule) — 4x fewer VMEM insts, better DRAM pages.
// Thread c: n-quad (c&63)*4, k-rows (c>>6)*8+jj (jj=0..7) -> 8 x f4 loads.
template<int K, int N, bool GELU>
__global__ __launch_bounds__(512, 2)
void moe_gemm(const u16* __restrict__ Abf, const float* __restrict__ Bf,
              u16* __restrict__ outp)
{
  constexpr int BM = 256, BN = 256, BK = 64;
  constexpr int NB = N / BN;                  // n0-blocks per expert
  constexpr int NT = K / BK;                  // K-steps
  constexpr int NF = 8;                       // b-fragments per wave
  constexpr int ABYTES = BM * 128;            // one As buffer (32 KB)
  __shared__ __align__(16) char lds[2 * ABYTES + BN * 128];  // 96 KB
  char* Bs = lds + 2 * ABYTES;     // Bs[n]: 64 bf16 (k-contig), chunk XOR (n&7)

  // XCD swizzle, n0 innermost: co-resident blocks on an XCD share A panels.
  const int d = blockIdx.y * NB + blockIdx.x;
  const int x = d & 7, j = d >> 3;
  const int e  = x * (NE / 8) + j / NB;
  const int n0 = (j % NB) * BN;
  const int row0 = e * PER_E;
  const int tid  = threadIdx.x;
  const int lane = tid & 63, wid = tid >> 6;
  const int wr   = wid >> 1, wc = wid & 1;    // 4x2 waves: 64 x 128 each

  const u16*   Arow = Abf + (size_t)row0 * K;
  const float* Bsrc = Bf + (size_t)e * K * N + n0;

  const int nq = (tid & 63) * 4;              // n-quad base for B staging
  const int kg = tid >> 6;                    // k-octet group (0..7)

  auto stageA = [&](int buf, int k0) {
    char* dst = lds + buf * ABYTES;
    #pragma unroll
    for (int i = 0; i < 4; ++i) {
      int c = i * 512 + tid;
      int r = c >> 3, kc = c & 7;
      int kswz = kc ^ (r & 7);
      __builtin_amdgcn_global_load_lds(
          (const void*)(Arow + (size_t)r * K + k0 + kswz * 8),
          (void*)(dst + c * 16), 16, 0, 0);
    }
  };
  // B-prefetch: 8 x dwordx4; br4[jj] = B[k0+kg*8+jj][nq..nq+3]
  auto loadB = [&](f4* br4, int k0) {
    #pragma unroll
    for (int jj = 0; jj < 8; ++jj)
      br4[jj] = *(const f4*)(Bsrc + (size_t)(k0 + kg * 8 + jj) * N + nq);
  };
  // B-publish: per n in quad, pack 8 k-values (k-adjacent cvt_pk pairs) into
  // one uint4 = chunk kg of row n, swizzled.
  auto writeB = [&](const f4* br4) {
    #pragma unroll
    for (int i = 0; i < 4; ++i) {
      int n = nq + i;
      u32 q[4];
      #pragma unroll
      for (int jj = 0; jj < 4; ++jj)
        q[jj] = pk2(br4[2 * jj][i], br4[2 * jj + 1][i]);
      *(uint4*)(Bs + n * 128 + ((kg * 16) ^ ((n & 7) << 4))) = *(uint4*)q;
    }
  };

  f4 acc[4][NF] = {};
  f4 breg[8];

  // ---- prologue: B(0)[8] + A(0)[4] issued; vmcnt(4) retires B(0) ----
  loadB(breg, 0);
  __builtin_amdgcn_sched_barrier(0);
  stageA(0, 0);
  asm volatile("s_waitcnt vmcnt(4)" ::: "memory");   // B(0) ready; A(0) flies
  __builtin_amdgcn_sched_barrier(0);
  writeB(breg);
  asm volatile("s_waitcnt lgkmcnt(0)" ::: "memory");
  __builtin_amdgcn_sched_barrier(0);
  __builtin_amdgcn_s_barrier();
  __builtin_amdgcn_sched_barrier(0);

  int cur = 0;
  for (int t = 0; t < NT; ++t) {
    const char* As = lds + cur * ABYTES;
    if (t + 1 < NT) {
      loadB(breg, (t + 1) * BK);
      __builtin_amdgcn_sched_barrier(0);
      stageA(cur ^ 1, (t + 1) * BK);
      asm volatile("s_waitcnt vmcnt(12)" ::: "memory");  // A(t) landed; 12 fly
    } else {
      asm volatile("s_waitcnt vmcnt(0)" ::: "memory");
    }
    __builtin_amdgcn_sched_barrier(0);
    __builtin_amdgcn_s_setprio(1);
    #pragma unroll
    for (int kk = 0; kk < 2; ++kk) {
      int kByte = kk * 64 + ((lane >> 4) << 4);
      bh8 a[4], b[NF];
      #pragma unroll
      for (int m = 0; m < 4; ++m) {
        int r = wr * 64 + m * 16 + (lane & 15);
        a[m] = *(const bh8*)(As + r * 128 + (kByte ^ ((r & 7) << 4)));
      }
      #pragma unroll
      for (int n = 0; n < NF; ++n) {
        int r = wc * 128 + n * 16 + (lane & 15);
        b[n] = *(const bh8*)(Bs + r * 128 + (kByte ^ ((r & 7) << 4)));
      }
      #pragma unroll
      for (int m = 0; m < 4; ++m)
        #pragma unroll
        for (int n = 0; n < NF; ++n)
          acc[m][n] = __builtin_amdgcn_mfma_f32_16x16x32_bf16(a[m], b[n], acc[m][n], 0, 0, 0);
    }
    __builtin_amdgcn_s_setprio(0);
    __builtin_amdgcn_s_barrier();          // done reading Bs
    __builtin_amdgcn_sched_barrier(0);
    if (t + 1 < NT) {
      asm volatile("s_waitcnt vmcnt(4)" ::: "memory");   // B(t+1) ready; A(t+1) flies
      __builtin_amdgcn_sched_barrier(0);
      writeB(breg);
      asm volatile("s_waitcnt lgkmcnt(0)" ::: "memory");
      __builtin_amdgcn_sched_barrier(0);
      __builtin_amdgcn_s_barrier();        // Bs(t+1) published; A(t+1) in flight
      __builtin_amdgcn_sched_barrier(0);
      cur ^= 1;
    }
  }

  // ---- epilogue: C layout (m89) col = lane&15, row = (lane>>4)*4 + j ----
  #pragma unroll
  for (int m = 0; m < 4; ++m) {
    #pragma unroll
    for (int n = 0; n < NF; ++n) {
      int rowb = wr * 64 + m * 16 + ((lane >> 4) << 2);
      int col  = n0 + wc * 128 + n * 16 + (lane & 15);
      #pragma unroll
      for (int jj = 0; jj < 4; ++jj) {
        float xv = acc[m][n][jj];
        if (GELU) {
          float y = fminf(fmaxf(xv, -8.f), 8.f);
          float u = 0.7978845608f * (y + 0.044715f * y * y * y);
          float t2 = __expf(-2.f * u);
          float g = __fdividef(y, 1.f + t2);
          outp[(size_t)(row0 + rowb + jj) * N + col] = f2bf(g);
        } else {
          outp[(size_t)(row0 + rowb + jj) * N + col] = f2bf(xv);
        }
      }
    }
  }
}

// out[t][:] = h2[sidx[2t]][:] + h2[sidx[2t+1]][:]   (h2 bf16; out f32)
__global__ void k_reduce(const u16* __restrict__ h2, const int* __restrict__ sidx,
                         float* __restrict__ out) {
  for (int i = blockIdx.x * 256 + threadIdx.x; i < NTOK * (HD / 4);
       i += 2048 * 256) {
    int t = i >> 8, c = i & 255;
    const u16* r0 = h2 + (size_t)sidx[2 * t] * HD + c * 4;
    const u16* r1 = h2 + (size_t)sidx[2 * t + 1] * HD + c * 4;
    u16 a0[4], a1[4];
    *(uint2*)a0 = *(const uint2*)r0;
    *(uint2*)a1 = *(const uint2*)r1;
    f4 s;
    #pragma unroll
    for (int jj = 0; jj < 4; ++jj) s[jj] = bf2f(a0[jj]) + bf2f(a1[jj]);
    *(f4*)(out + (size_t)t * HD + c * 4) = s;
  }
}

extern "C" void kernel_launch(void* const* d_in, const int* in_sizes, int n_in,
                              void* d_out, int out_size, void* d_ws, size_t ws_size,
                              hipStream_t stream) {
  const float* inp  = (const float*)d_in[0];
  const float* w1   = (const float*)d_in[1];
  const float* w2   = (const float*)d_in[2];
  const int*   sidx = (const int*)d_in[3];
  float* out = (float*)d_out;

  char* ws   = (char*)d_ws;
  int*   s2t = (int*)ws;                                          // 64 KB
  u16*   X   = (u16*)(ws + (1 << 20));                            // 32 MB bf16 [MTOT][HD]
  u16*   act = (u16*)(ws + (1 << 20) + (32u << 20));              // 64 MB bf16 [MTOT][FFND]
  u16*   h2  = (u16*)(ws + (1 << 20) + (96u << 20));              // 32 MB bf16 [MTOT][HD]

  k_build_s2t<<<MTOT / 256, 256, 0, stream>>>(sidx, s2t);
  k_gather_x<<<2048, 256, 0, stream>>>(inp, s2t, X);
  moe_gemm<HD, FFND, true><<<dim3(FFND / 256, NE), 512, 0, stream>>>(X, w1, act);
  moe_gemm<FFND, HD, false><<<dim3(HD / 256, NE), 512, 0, stream>>>(act, w2, h2);
  k_reduce<<<2048, 256, 0, stream>>>(h2, sidx, out);
}

// Round 17
// 273.748 us; speedup vs baseline: 3.3976x; 1.0432x over previous
//
#include <hip/hip_runtime.h>
#include <hip/hip_bf16.h>
#include <math.h>

#define NTOK 8192
#define HD   1024
#define FFND 2048
#define NE   64
#define MTOT 16384   // NTOK * TOPK
#define PER_E 256    // MTOT / NE

typedef __attribute__((ext_vector_type(8))) short bh8;
typedef __attribute__((ext_vector_type(4))) float f4;
typedef unsigned short u16;
typedef unsigned int   u32;

__device__ __forceinline__ u16 f2bf(float f) {
  union { float f; u32 u; } x; x.f = f;
  u32 r = x.u + 0x7fffu + ((x.u >> 16) & 1u);   // round-nearest-even
  return (u16)(r >> 16);
}

__device__ __forceinline__ float bf2f(u16 b) {
  union { u32 u; float f; } x; x.u = ((u32)b) << 16; return x.f;
}

__device__ __forceinline__ u32 pk2(float lo, float hi) {
  __hip_bfloat162 h = __float22bfloat162_rn(make_float2(lo, hi));
  union { __hip_bfloat162 h; u32 u; } c; c.h = h;
  return c.u;
}

// slot -> source token map. scatter_index flat: sidx[t*2+k] = slot.
__global__ void k_build_s2t(const int* __restrict__ sidx, int* __restrict__ s2t) {
  int i = blockIdx.x * 256 + threadIdx.x;   // i in [0, MTOT)
  s2t[sidx[i]] = i >> 1;
}

// Gather + f32->bf16 convert: X[slot][h] = bf16(inputs[s2t[slot]][h])
__global__ void k_gather_x(const float* __restrict__ inp, const int* __restrict__ s2t,
                           u16* __restrict__ X) {
  for (int idx = blockIdx.x * 256 + threadIdx.x; idx < MTOT * (HD / 8);
       idx += 2048 * 256) {
    int slot = idx >> 7;                      // HD/8 = 128 chunks per row
    int c    = idx & 127;
    const float* src = inp + (size_t)s2t[slot] * HD + c * 8;
    float v[8];
    *(f4*)(v)     = *(const f4*)(src);
    *(f4*)(v + 4) = *(const f4*)(src + 4);
    u32 o[4];
    #pragma unroll
    for (int j = 0; j < 4; ++j) o[j] = pk2(v[2 * j], v[2 * j + 1]);
    *(uint4*)(X + (size_t)slot * HD + c * 8) = *(uint4*)o;
  }
}

// Grouped GEMM, BM=BN=256 (weights read once), 512 thr (4x2 waves, 64x128 each),
// 96 KB LDS, depth-1 prefetch with COUNTED vmcnt.
// B loaded with NON-TEMPORAL dwordx4 (single-use weight stream must not evict
// the L2/L3-resident X/act panels that A re-reads depend on).
template<int K, int N, bool GELU>
__global__ __launch_bounds__(512, 2)
void moe_gemm(const u16* __restrict__ Abf, const float* __restrict__ Bf,
              u16* __restrict__ outp)
{
  constexpr int BM = 256, BN = 256, BK = 64;
  constexpr int NB = N / BN;                  // n0-blocks per expert
  constexpr int NT = K / BK;                  // K-steps
  constexpr int NF = 8;                       // b-fragments per wave
  constexpr int ABYTES = BM * 128;            // one As buffer (32 KB)
  __shared__ __align__(16) char lds[2 * ABYTES + BN * 128];  // 96 KB
  char* Bs = lds + 2 * ABYTES;     // Bs[n]: 64 bf16 (k-contig), chunk XOR (n&7)

  // XCD swizzle, n0 innermost: co-resident blocks on an XCD share A panels.
  const int d = blockIdx.y * NB + blockIdx.x;
  const int x = d & 7, j = d >> 3;
  const int e  = x * (NE / 8) + j / NB;
  const int n0 = (j % NB) * BN;
  const int row0 = e * PER_E;
  const int tid  = threadIdx.x;
  const int lane = tid & 63, wid = tid >> 6;
  const int wr   = wid >> 1, wc = wid & 1;    // 4x2 waves: 64 x 128 each

  const u16*   Arow = Abf + (size_t)row0 * K;
  const float* Bsrc = Bf + (size_t)e * K * N + n0;

  const int nq = (tid & 63) * 4;              // n-quad base for B staging
  const int kg = tid >> 6;                    // k-octet group (0..7)

  auto stageA = [&](int buf, int k0) {
    char* dst = lds + buf * ABYTES;
    #pragma unroll
    for (int i = 0; i < 4; ++i) {
      int c = i * 512 + tid;
      int r = c >> 3, kc = c & 7;
      int kswz = kc ^ (r & 7);
      __builtin_amdgcn_global_load_lds(
          (const void*)(Arow + (size_t)r * K + k0 + kswz * 8),
          (void*)(dst + c * 16), 16, 0, 0);
    }
  };
  // B-prefetch: 8 x NON-TEMPORAL dwordx4; br4[jj] = B[k0+kg*8+jj][nq..nq+3]
  auto loadB = [&](f4* br4, int k0) {
    #pragma unroll
    for (int jj = 0; jj < 8; ++jj)
      br4[jj] = __builtin_nontemporal_load(
          (const f4*)(Bsrc + (size_t)(k0 + kg * 8 + jj) * N + nq));
  };
  // B-publish: per n in quad, pack 8 k-values (k-adjacent cvt_pk pairs) into
  // one uint4 = chunk kg of row n, swizzled.
  auto writeB = [&](const f4* br4) {
    #pragma unroll
    for (int i = 0; i < 4; ++i) {
      int n = nq + i;
      u32 q[4];
      #pragma unroll
      for (int jj = 0; jj < 4; ++jj)
        q[jj] = pk2(br4[2 * jj][i], br4[2 * jj + 1][i]);
      *(uint4*)(Bs + n * 128 + ((kg * 16) ^ ((n & 7) << 4))) = *(uint4*)q;
    }
  };

  f4 acc[4][NF] = {};
  f4 breg[8];

  // ---- prologue: B(0)[8] + A(0)[4] issued; vmcnt(4) retires B(0) ----
  loadB(breg, 0);
  __builtin_amdgcn_sched_barrier(0);
  stageA(0, 0);
  asm volatile("s_waitcnt vmcnt(4)" ::: "memory");   // B(0) ready; A(0) flies
  __builtin_amdgcn_sched_barrier(0);
  writeB(breg);
  asm volatile("s_waitcnt lgkmcnt(0)" ::: "memory");
  __builtin_amdgcn_sched_barrier(0);
  __builtin_amdgcn_s_barrier();
  __builtin_amdgcn_sched_barrier(0);

  int cur = 0;
  for (int t = 0; t < NT; ++t) {
    const char* As = lds + cur * ABYTES;
    if (t + 1 < NT) {
      loadB(breg, (t + 1) * BK);
      __builtin_amdgcn_sched_barrier(0);
      stageA(cur ^ 1, (t + 1) * BK);
      asm volatile("s_waitcnt vmcnt(12)" ::: "memory");  // A(t) landed; 12 fly
    } else {
      asm volatile("s_waitcnt vmcnt(0)" ::: "memory");
    }
    __builtin_amdgcn_sched_barrier(0);
    __builtin_amdgcn_s_setprio(1);
    #pragma unroll
    for (int kk = 0; kk < 2; ++kk) {
      int kByte = kk * 64 + ((lane >> 4) << 4);
      bh8 a[4], b[NF];
      #pragma unroll
      for (int m = 0; m < 4; ++m) {
        int r = wr * 64 + m * 16 + (lane & 15);
        a[m] = *(const bh8*)(As + r * 128 + (kByte ^ ((r & 7) << 4)));
      }
      #pragma unroll
      for (int n = 0; n < NF; ++n) {
        int r = wc * 128 + n * 16 + (lane & 15);
        b[n] = *(const bh8*)(Bs + r * 128 + (kByte ^ ((r & 7) << 4)));
      }
      #pragma unroll
      for (int m = 0; m < 4; ++m)
        #pragma unroll
        for (int n = 0; n < NF; ++n)
          acc[m][n] = __builtin_amdgcn_mfma_f32_16x16x32_bf16(a[m], b[n], acc[m][n], 0, 0, 0);
    }
    __builtin_amdgcn_s_setprio(0);
    __builtin_amdgcn_s_barrier();          // done reading Bs
    __builtin_amdgcn_sched_barrier(0);
    if (t + 1 < NT) {
      asm volatile("s_waitcnt vmcnt(4)" ::: "memory");   // B(t+1) ready; A(t+1) flies
      __builtin_amdgcn_sched_barrier(0);
      writeB(breg);
      asm volatile("s_waitcnt lgkmcnt(0)" ::: "memory");
      __builtin_amdgcn_sched_barrier(0);
      __builtin_amdgcn_s_barrier();        // Bs(t+1) published; A(t+1) in flight
      __builtin_amdgcn_sched_barrier(0);
      cur ^= 1;
    }
  }

  // ---- epilogue: C layout (m89) col = lane&15, row = (lane>>4)*4 + j ----
  #pragma unroll
  for (int m = 0; m < 4; ++m) {
    #pragma unroll
    for (int n = 0; n < NF; ++n) {
      int rowb = wr * 64 + m * 16 + ((lane >> 4) << 2);
      int col  = n0 + wc * 128 + n * 16 + (lane & 15);
      #pragma unroll
      for (int jj = 0; jj < 4; ++jj) {
        float xv = acc[m][n][jj];
        if (GELU) {
          float y = fminf(fmaxf(xv, -8.f), 8.f);
          float u = 0.7978845608f * (y + 0.044715f * y * y * y);
          float t2 = __expf(-2.f * u);
          float g = __fdividef(y, 1.f + t2);
          outp[(size_t)(row0 + rowb + jj) * N + col] = f2bf(g);
        } else {
          outp[(size_t)(row0 + rowb + jj) * N + col] = f2bf(xv);
        }
      }
    }
  }
}

// out[t][:] = h2[sidx[2t]][:] + h2[sidx[2t+1]][:]   (h2 bf16; out f32)
__global__ void k_reduce(const u16* __restrict__ h2, const int* __restrict__ sidx,
                         float* __restrict__ out) {
  for (int i = blockIdx.x * 256 + threadIdx.x; i < NTOK * (HD / 4);
       i += 2048 * 256) {
    int t = i >> 8, c = i & 255;
    const u16* r0 = h2 + (size_t)sidx[2 * t] * HD + c * 4;
    const u16* r1 = h2 + (size_t)sidx[2 * t + 1] * HD + c * 4;
    u16 a0[4], a1[4];
    *(uint2*)a0 = *(const uint2*)r0;
    *(uint2*)a1 = *(const uint2*)r1;
    f4 s;
    #pragma unroll
    for (int jj = 0; jj < 4; ++jj) s[jj] = bf2f(a0[jj]) + bf2f(a1[jj]);
    *(f4*)(out + (size_t)t * HD + c * 4) = s;
  }
}

extern "C" void kernel_launch(void* const* d_in, const int* in_sizes, int n_in,
                              void* d_out, int out_size, void* d_ws, size_t ws_size,
                              hipStream_t stream) {
  const float* inp  = (const float*)d_in[0];
  const float* w1   = (const float*)d_in[1];
  const float* w2   = (const float*)d_in[2];
  const int*   sidx = (const int*)d_in[3];
  float* out = (float*)d_out;

  char* ws   = (char*)d_ws;
  int*   s2t = (int*)ws;                                          // 64 KB
  u16*   X   = (u16*)(ws + (1 << 20));                            // 32 MB bf16 [MTOT][HD]
  u16*   act = (u16*)(ws + (1 << 20) + (32u << 20));              // 64 MB bf16 [MTOT][FFND]
  u16*   h2  = (u16*)(ws + (1 << 20) + (96u << 20));              // 32 MB bf16 [MTOT][HD]

  k_build_s2t<<<MTOT / 256, 256, 0, stream>>>(sidx, s2t);
  k_gather_x<<<2048, 256, 0, stream>>>(inp, s2t, X);
  moe_gemm<HD, FFND, true><<<dim3(FFND / 256, NE), 512, 0, stream>>>(X, w1, act);
  moe_gemm<FFND, HD, false><<<dim3(HD / 256, NE), 512, 0, stream>>>(act, w2, h2);
  k_reduce<<<2048, 256, 0, stream>>>(h2, sidx, out);
}

// Round 18
// 269.288 us; speedup vs baseline: 3.4539x; 1.0166x over previous
//
#include <hip/hip_runtime.h>
#include <hip/hip_bf16.h>
#include <math.h>

#define NTOK 8192
#define HD   1024
#define FFND 2048
#define NE   64
#define MTOT 16384   // NTOK * TOPK
#define PER_E 256    // MTOT / NE

typedef __attribute__((ext_vector_type(8))) short bh8;
typedef __attribute__((ext_vector_type(4))) float f4;
typedef unsigned short u16;
typedef unsigned int   u32;

#define SB0 __builtin_amdgcn_sched_barrier(0)

__device__ __forceinline__ u16 f2bf(float f) {
  union { float f; u32 u; } x; x.f = f;
  u32 r = x.u + 0x7fffu + ((x.u >> 16) & 1u);   // round-nearest-even
  return (u16)(r >> 16);
}

__device__ __forceinline__ float bf2f(u16 b) {
  union { u32 u; float f; } x; x.u = ((u32)b) << 16; return x.f;
}

__device__ __forceinline__ u32 pk2(float lo, float hi) {
  __hip_bfloat162 h = __float22bfloat162_rn(make_float2(lo, hi));
  union { __hip_bfloat162 h; u32 u; } c; c.h = h;
  return c.u;
}

// slot -> source token map. scatter_index flat: sidx[t*2+k] = slot.
__global__ void k_build_s2t(const int* __restrict__ sidx, int* __restrict__ s2t) {
  int i = blockIdx.x * 256 + threadIdx.x;   // i in [0, MTOT)
  s2t[sidx[i]] = i >> 1;
}

// GEMM1 with FUSED gather: A rows come straight from inp[s2t[row]] (f32),
// reg-staged + cvt_pk -> As (same XOR-preswizzled chunk layout as
// global_load_lds dest). Saves the 64 MB X round-trip and one launch.
// Single As/Bs buffers (64 KB): loads(t+1) issued before MFMA(t); writes after
// the read-barrier (vmcnt(0) there is free — loads are one full phase old).
template<int K, int N>
__global__ __launch_bounds__(512, 2)
void moe_gemm1(const float* __restrict__ inp, const int* __restrict__ s2t,
               const float* __restrict__ Bf, u16* __restrict__ actout)
{
  constexpr int BM = 256, BN = 256, BK = 64;
  constexpr int NB = N / BN;
  constexpr int NT = K / BK;
  constexpr int NF = 8;
  constexpr int ABYTES = BM * 128;            // 32 KB
  __shared__ __align__(16) char lds[ABYTES + BN * 128];  // 64 KB
  char* Bs = lds + ABYTES;

  const int d = blockIdx.y * NB + blockIdx.x;
  const int x = d & 7, j = d >> 3;
  const int e  = x * (NE / 8) + j / NB;
  const int n0 = (j % NB) * BN;
  const int row0 = e * PER_E;
  const int tid  = threadIdx.x;
  const int lane = tid & 63, wid = tid >> 6;
  const int wr   = wid >> 1, wc = wid & 1;    // 4x2 waves: 64 x 128 each

  const float* Bsrc = Bf + (size_t)e * K * N + n0;
  const int nq = (tid & 63) * 4;              // B: n-quad base
  const int kg = tid >> 6;                    // B: k-octet group

  // my 4 A-rows and their source tokens
  int arow[4]; const float* asrc[4];
  #pragma unroll
  for (int i = 0; i < 4; ++i) {
    int c = i * 512 + tid;
    arow[i] = c >> 3;
    asrc[i] = inp + (size_t)s2t[row0 + arow[i]] * K;
  }

  auto loadA = [&](f4* ar, int k0) {
    #pragma unroll
    for (int i = 0; i < 4; ++i) {
      int c = i * 512 + tid;
      int kc = c & 7, r = arow[i];
      int kswz = kc ^ (r & 7);
      const float* p = asrc[i] + k0 + kswz * 8;
      ar[i * 2]     = *(const f4*)(p);
      ar[i * 2 + 1] = *(const f4*)(p + 4);
    }
  };
  auto writeA = [&](const f4* ar) {
    #pragma unroll
    for (int i = 0; i < 4; ++i) {
      int c = i * 512 + tid;
      u32 q[4];
      q[0] = pk2(ar[i * 2][0],     ar[i * 2][1]);
      q[1] = pk2(ar[i * 2][2],     ar[i * 2][3]);
      q[2] = pk2(ar[i * 2 + 1][0], ar[i * 2 + 1][1]);
      q[3] = pk2(ar[i * 2 + 1][2], ar[i * 2 + 1][3]);
      *(uint4*)(lds + c * 16) = *(uint4*)q;   // linear dest, src pre-swizzled
    }
  };
  auto loadB = [&](f4* br4, int k0) {
    #pragma unroll
    for (int jj = 0; jj < 8; ++jj)
      br4[jj] = __builtin_nontemporal_load(
          (const f4*)(Bsrc + (size_t)(k0 + kg * 8 + jj) * N + nq));
  };
  auto writeB = [&](const f4* br4) {
    #pragma unroll
    for (int i = 0; i < 4; ++i) {
      int n = nq + i;
      u32 q[4];
      #pragma unroll
      for (int jj = 0; jj < 4; ++jj)
        q[jj] = pk2(br4[2 * jj][i], br4[2 * jj + 1][i]);
      *(uint4*)(Bs + n * 128 + ((kg * 16) ^ ((n & 7) << 4))) = *(uint4*)q;
    }
  };

  f4 acc[4][NF] = {};
  f4 breg[8], areg[8];

  // ---- prologue: tile 0 ----
  loadB(breg, 0); SB0;
  loadA(areg, 0); SB0;
  asm volatile("s_waitcnt vmcnt(0)" ::: "memory"); SB0;
  writeB(breg);
  writeA(areg);
  asm volatile("s_waitcnt lgkmcnt(0)" ::: "memory"); SB0;
  __builtin_amdgcn_s_barrier(); SB0;

  for (int t = 0; t < NT; ++t) {
    if (t + 1 < NT) {
      loadB(breg, (t + 1) * BK); SB0;
      loadA(areg, (t + 1) * BK); SB0;
    }
    __builtin_amdgcn_s_setprio(1);
    #pragma unroll
    for (int kk = 0; kk < 2; ++kk) {
      int kByte = kk * 64 + ((lane >> 4) << 4);
      bh8 a[4], b[NF];
      #pragma unroll
      for (int m = 0; m < 4; ++m) {
        int r = wr * 64 + m * 16 + (lane & 15);
        a[m] = *(const bh8*)(lds + r * 128 + (kByte ^ ((r & 7) << 4)));
      }
      #pragma unroll
      for (int n = 0; n < NF; ++n) {
        int r = wc * 128 + n * 16 + (lane & 15);
        b[n] = *(const bh8*)(Bs + r * 128 + (kByte ^ ((r & 7) << 4)));
      }
      #pragma unroll
      for (int m = 0; m < 4; ++m)
        #pragma unroll
        for (int n = 0; n < NF; ++n)
          acc[m][n] = __builtin_amdgcn_mfma_f32_16x16x32_bf16(a[m], b[n], acc[m][n], 0, 0, 0);
    }
    __builtin_amdgcn_s_setprio(0);
    __builtin_amdgcn_s_barrier(); SB0;       // all waves done reading As/Bs
    if (t + 1 < NT) {
      asm volatile("s_waitcnt vmcnt(0)" ::: "memory"); SB0;  // regs ready (1 phase old)
      writeB(breg);
      writeA(areg);
      asm volatile("s_waitcnt lgkmcnt(0)" ::: "memory"); SB0;
      __builtin_amdgcn_s_barrier(); SB0;     // tile t+1 published
    }
  }

  // ---- epilogue: GELU + store (C layout m89) ----
  #pragma unroll
  for (int m = 0; m < 4; ++m) {
    #pragma unroll
    for (int n = 0; n < NF; ++n) {
      int rowb = wr * 64 + m * 16 + ((lane >> 4) << 2);
      int col  = n0 + wc * 128 + n * 16 + (lane & 15);
      #pragma unroll
      for (int jj = 0; jj < 4; ++jj) {
        float xv = acc[m][n][jj];
        float y = fminf(fmaxf(xv, -8.f), 8.f);
        float u = 0.7978845608f * (y + 0.044715f * y * y * y);
        float t2 = __expf(-2.f * u);
        float g = __fdividef(y, 1.f + t2);
        actout[(size_t)(row0 + rowb + jj) * N + col] = f2bf(g);
      }
    }
  }
}

// GEMM2 (round-17 proven form): A = act bf16 via global_load_lds dbuf,
// B = w2 NT-dwordx4, counted vmcnt; writes bf16 partials to h2.
template<int K, int N>
__global__ __launch_bounds__(512, 2)
void moe_gemm2(const u16* __restrict__ Abf, const float* __restrict__ Bf,
               u16* __restrict__ outp)
{
  constexpr int BM = 256, BN = 256, BK = 64;
  constexpr int NB = N / BN;
  constexpr int NT = K / BK;
  constexpr int NF = 8;
  constexpr int ABYTES = BM * 128;
  __shared__ __align__(16) char lds[2 * ABYTES + BN * 128];  // 96 KB
  char* Bs = lds + 2 * ABYTES;

  const int d = blockIdx.y * NB + blockIdx.x;
  const int x = d & 7, j = d >> 3;
  const int e  = x * (NE / 8) + j / NB;
  const int n0 = (j % NB) * BN;
  const int row0 = e * PER_E;
  const int tid  = threadIdx.x;
  const int lane = tid & 63, wid = tid >> 6;
  const int wr   = wid >> 1, wc = wid & 1;

  const u16*   Arow = Abf + (size_t)row0 * K;
  const float* Bsrc = Bf + (size_t)e * K * N + n0;
  const int nq = (tid & 63) * 4;
  const int kg = tid >> 6;

  auto stageA = [&](int buf, int k0) {
    char* dst = lds + buf * ABYTES;
    #pragma unroll
    for (int i = 0; i < 4; ++i) {
      int c = i * 512 + tid;
      int r = c >> 3, kc = c & 7;
      int kswz = kc ^ (r & 7);
      __builtin_amdgcn_global_load_lds(
          (const void*)(Arow + (size_t)r * K + k0 + kswz * 8),
          (void*)(dst + c * 16), 16, 0, 0);
    }
  };
  auto loadB = [&](f4* br4, int k0) {
    #pragma unroll
    for (int jj = 0; jj < 8; ++jj)
      br4[jj] = __builtin_nontemporal_load(
          (const f4*)(Bsrc + (size_t)(k0 + kg * 8 + jj) * N + nq));
  };
  auto writeB = [&](const f4* br4) {
    #pragma unroll
    for (int i = 0; i < 4; ++i) {
      int n = nq + i;
      u32 q[4];
      #pragma unroll
      for (int jj = 0; jj < 4; ++jj)
        q[jj] = pk2(br4[2 * jj][i], br4[2 * jj + 1][i]);
      *(uint4*)(Bs + n * 128 + ((kg * 16) ^ ((n & 7) << 4))) = *(uint4*)q;
    }
  };

  f4 acc[4][NF] = {};
  f4 breg[8];

  loadB(breg, 0); SB0;
  stageA(0, 0);
  asm volatile("s_waitcnt vmcnt(4)" ::: "memory"); SB0;
  writeB(breg);
  asm volatile("s_waitcnt lgkmcnt(0)" ::: "memory"); SB0;
  __builtin_amdgcn_s_barrier(); SB0;

  int cur = 0;
  for (int t = 0; t < NT; ++t) {
    const char* As = lds + cur * ABYTES;
    if (t + 1 < NT) {
      loadB(breg, (t + 1) * BK); SB0;
      stageA(cur ^ 1, (t + 1) * BK);
      asm volatile("s_waitcnt vmcnt(12)" ::: "memory");
    } else {
      asm volatile("s_waitcnt vmcnt(0)" ::: "memory");
    }
    SB0;
    __builtin_amdgcn_s_setprio(1);
    #pragma unroll
    for (int kk = 0; kk < 2; ++kk) {
      int kByte = kk * 64 + ((lane >> 4) << 4);
      bh8 a[4], b[NF];
      #pragma unroll
      for (int m = 0; m < 4; ++m) {
        int r = wr * 64 + m * 16 + (lane & 15);
        a[m] = *(const bh8*)(As + r * 128 + (kByte ^ ((r & 7) << 4)));
      }
      #pragma unroll
      for (int n = 0; n < NF; ++n) {
        int r = wc * 128 + n * 16 + (lane & 15);
        b[n] = *(const bh8*)(Bs + r * 128 + (kByte ^ ((r & 7) << 4)));
      }
      #pragma unroll
      for (int m = 0; m < 4; ++m)
        #pragma unroll
        for (int n = 0; n < NF; ++n)
          acc[m][n] = __builtin_amdgcn_mfma_f32_16x16x32_bf16(a[m], b[n], acc[m][n], 0, 0, 0);
    }
    __builtin_amdgcn_s_setprio(0);
    __builtin_amdgcn_s_barrier(); SB0;
    if (t + 1 < NT) {
      asm volatile("s_waitcnt vmcnt(4)" ::: "memory"); SB0;
      writeB(breg);
      asm volatile("s_waitcnt lgkmcnt(0)" ::: "memory"); SB0;
      __builtin_amdgcn_s_barrier(); SB0;
      cur ^= 1;
    }
  }

  #pragma unroll
  for (int m = 0; m < 4; ++m) {
    #pragma unroll
    for (int n = 0; n < NF; ++n) {
      int rowb = wr * 64 + m * 16 + ((lane >> 4) << 2);
      int col  = n0 + wc * 128 + n * 16 + (lane & 15);
      #pragma unroll
      for (int jj = 0; jj < 4; ++jj)
        outp[(size_t)(row0 + rowb + jj) * N + col] = f2bf(acc[m][n][jj]);
    }
  }
}

// out[t][:] = h2[sidx[2t]][:] + h2[sidx[2t+1]][:]   (h2 bf16; out f32)
__global__ void k_reduce(const u16* __restrict__ h2, const int* __restrict__ sidx,
                         float* __restrict__ out) {
  for (int i = blockIdx.x * 256 + threadIdx.x; i < NTOK * (HD / 4);
       i += 2048 * 256) {
    int t = i >> 8, c = i & 255;
    const u16* r0 = h2 + (size_t)sidx[2 * t] * HD + c * 4;
    const u16* r1 = h2 + (size_t)sidx[2 * t + 1] * HD + c * 4;
    u16 a0[4], a1[4];
    *(uint2*)a0 = *(const uint2*)r0;
    *(uint2*)a1 = *(const uint2*)r1;
    f4 s;
    #pragma unroll
    for (int jj = 0; jj < 4; ++jj) s[jj] = bf2f(a0[jj]) + bf2f(a1[jj]);
    *(f4*)(out + (size_t)t * HD + c * 4) = s;
  }
}

extern "C" void kernel_launch(void* const* d_in, const int* in_sizes, int n_in,
                              void* d_out, int out_size, void* d_ws, size_t ws_size,
                              hipStream_t stream) {
  const float* inp  = (const float*)d_in[0];
  const float* w1   = (const float*)d_in[1];
  const float* w2   = (const float*)d_in[2];
  const int*   sidx = (const int*)d_in[3];
  float* out = (float*)d_out;

  char* ws   = (char*)d_ws;
  int*   s2t = (int*)ws;                                          // 64 KB
  u16*   act = (u16*)(ws + (1 << 20) + (32u << 20));              // 64 MB bf16 [MTOT][FFND]
  u16*   h2  = (u16*)(ws + (1 << 20) + (96u << 20));              // 32 MB bf16 [MTOT][HD]

  k_build_s2t<<<MTOT / 256, 256, 0, stream>>>(sidx, s2t);
  moe_gemm1<HD, FFND><<<dim3(FFND / 256, NE), 512, 0, stream>>>(inp, s2t, w1, act);
  moe_gemm2<FFND, HD><<<dim3(HD / 256, NE), 512, 0, stream>>>(act, w2, h2);
  k_reduce<<<2048, 256, 0, stream>>>(h2, sidx, out);
}

// Round 20
// 259.724 us; speedup vs baseline: 3.5810x; 1.0368x over previous
//
#include <hip/hip_runtime.h>
#include <hip/hip_bf16.h>
#include <math.h>

#define NTOK 8192
#define HD   1024
#define FFND 2048
#define NE   64
#define MTOT 16384   // NTOK * TOPK
#define PER_E 256    // MTOT / NE

typedef __attribute__((ext_vector_type(8))) short bh8;
typedef __attribute__((ext_vector_type(4))) float f4;
typedef __attribute__((ext_vector_type(2))) unsigned int u32x2;
typedef unsigned short u16;
typedef unsigned int   u32;

#define SB0 __builtin_amdgcn_sched_barrier(0)

__device__ __forceinline__ u16 f2bf(float f) {
  union { float f; u32 u; } x; x.f = f;
  u32 r = x.u + 0x7fffu + ((x.u >> 16) & 1u);   // round-nearest-even
  return (u16)(r >> 16);
}

__device__ __forceinline__ float bf2f(u16 b) {
  union { u32 u; float f; } x; x.u = ((u32)b) << 16; return x.f;
}

__device__ __forceinline__ u32 pk2(float lo, float hi) {
  __hip_bfloat162 h = __float22bfloat162_rn(make_float2(lo, hi));
  union { __hip_bfloat162 h; u32 u; } c; c.h = h;
  return c.u;
}

// slot -> source token map. scatter_index flat: sidx[t*2+k] = slot.
__global__ void k_build_s2t(const int* __restrict__ sidx, int* __restrict__ s2t) {
  int i = blockIdx.x * 256 + threadIdx.x;   // i in [0, MTOT)
  s2t[sidx[i]] = i >> 1;
}

// GEMM1 with FUSED gather: A rows straight from inp[s2t[row]] (f32),
// reg-staged + cvt_pk -> As (XOR-preswizzled chunk layout). Split counted
// drain: loadA (8, older) then loadB (8, newer); vmcnt(8) -> writeA overlaps
// B's tail latency; vmcnt(0) -> writeB.
template<int K, int N>
__global__ __launch_bounds__(512, 2)
void moe_gemm1(const float* __restrict__ inp, const int* __restrict__ s2t,
               const float* __restrict__ Bf, u16* __restrict__ actout)
{
  constexpr int BM = 256, BN = 256, BK = 64;
  constexpr int NB = N / BN;
  constexpr int NT = K / BK;
  constexpr int NF = 8;
  constexpr int ABYTES = BM * 128;            // 32 KB
  __shared__ __align__(16) char lds[ABYTES + BN * 128];  // 64 KB
  char* Bs = lds + ABYTES;

  const int d = blockIdx.y * NB + blockIdx.x;
  const int x = d & 7, j = d >> 3;
  const int e  = x * (NE / 8) + j / NB;
  const int n0 = (j % NB) * BN;
  const int row0 = e * PER_E;
  const int tid  = threadIdx.x;
  const int lane = tid & 63, wid = tid >> 6;
  const int wr   = wid >> 1, wc = wid & 1;    // 4x2 waves: 64 x 128 each

  const float* Bsrc = Bf + (size_t)e * K * N + n0;
  const int nq = (tid & 63) * 4;              // B: n-quad base
  const int kg = tid >> 6;                    // B: k-octet group

  // my 4 A-rows and their source tokens
  int arow[4]; const float* asrc[4];
  #pragma unroll
  for (int i = 0; i < 4; ++i) {
    int c = i * 512 + tid;
    arow[i] = c >> 3;
    asrc[i] = inp + (size_t)s2t[row0 + arow[i]] * K;
  }

  auto loadA = [&](f4* ar, int k0) {
    #pragma unroll
    for (int i = 0; i < 4; ++i) {
      int c = i * 512 + tid;
      int kc = c & 7, r = arow[i];
      int kswz = kc ^ (r & 7);
      const float* p = asrc[i] + k0 + kswz * 8;
      ar[i * 2]     = *(const f4*)(p);
      ar[i * 2 + 1] = *(const f4*)(p + 4);
    }
  };
  auto writeA = [&](const f4* ar) {
    #pragma unroll
    for (int i = 0; i < 4; ++i) {
      int c = i * 512 + tid;
      u32 q[4];
      q[0] = pk2(ar[i * 2][0],     ar[i * 2][1]);
      q[1] = pk2(ar[i * 2][2],     ar[i * 2][3]);
      q[2] = pk2(ar[i * 2 + 1][0], ar[i * 2 + 1][1]);
      q[3] = pk2(ar[i * 2 + 1][2], ar[i * 2 + 1][3]);
      *(uint4*)(lds + c * 16) = *(uint4*)q;   // linear dest, src pre-swizzled
    }
  };
  auto loadB = [&](f4* br4, int k0) {
    #pragma unroll
    for (int jj = 0; jj < 8; ++jj)
      br4[jj] = __builtin_nontemporal_load(
          (const f4*)(Bsrc + (size_t)(k0 + kg * 8 + jj) * N + nq));
  };
  auto writeB = [&](const f4* br4) {
    #pragma unroll
    for (int i = 0; i < 4; ++i) {
      int n = nq + i;
      u32 q[4];
      #pragma unroll
      for (int jj = 0; jj < 4; ++jj)
        q[jj] = pk2(br4[2 * jj][i], br4[2 * jj + 1][i]);
      *(uint4*)(Bs + n * 128 + ((kg * 16) ^ ((n & 7) << 4))) = *(uint4*)q;
    }
  };

  f4 acc[4][NF] = {};
  f4 breg[8], areg[8];

  // ---- prologue: tile 0 (A older, B newer) ----
  loadA(areg, 0); SB0;
  loadB(breg, 0); SB0;
  asm volatile("s_waitcnt vmcnt(8)" ::: "memory"); SB0;   // A ready
  writeA(areg);
  asm volatile("s_waitcnt vmcnt(0)" ::: "memory"); SB0;   // B ready
  writeB(breg);
  asm volatile("s_waitcnt lgkmcnt(0)" ::: "memory"); SB0;
  __builtin_amdgcn_s_barrier(); SB0;

  for (int t = 0; t < NT; ++t) {
    if (t + 1 < NT) {
      loadA(areg, (t + 1) * BK); SB0;
      loadB(breg, (t + 1) * BK); SB0;
    }
    __builtin_amdgcn_s_setprio(1);
    #pragma unroll
    for (int kk = 0; kk < 2; ++kk) {
      int kByte = kk * 64 + ((lane >> 4) << 4);
      bh8 a[4], b[NF];
      #pragma unroll
      for (int m = 0; m < 4; ++m) {
        int r = wr * 64 + m * 16 + (lane & 15);
        a[m] = *(const bh8*)(lds + r * 128 + (kByte ^ ((r & 7) << 4)));
      }
      #pragma unroll
      for (int n = 0; n < NF; ++n) {
        int r = wc * 128 + n * 16 + (lane & 15);
        b[n] = *(const bh8*)(Bs + r * 128 + (kByte ^ ((r & 7) << 4)));
      }
      #pragma unroll
      for (int m = 0; m < 4; ++m)
        #pragma unroll
        for (int n = 0; n < NF; ++n)
          acc[m][n] = __builtin_amdgcn_mfma_f32_16x16x32_bf16(a[m], b[n], acc[m][n], 0, 0, 0);
    }
    __builtin_amdgcn_s_setprio(0);
    __builtin_amdgcn_s_barrier(); SB0;       // all waves done reading As/Bs
    if (t + 1 < NT) {
      asm volatile("s_waitcnt vmcnt(8)" ::: "memory"); SB0;  // A(t+1) regs ready
      writeA(areg);                           // overlaps B's remaining latency
      asm volatile("s_waitcnt vmcnt(0)" ::: "memory"); SB0;  // B(t+1) regs ready
      writeB(breg);
      asm volatile("s_waitcnt lgkmcnt(0)" ::: "memory"); SB0;
      __builtin_amdgcn_s_barrier(); SB0;     // tile t+1 published
    }
  }

  // ---- epilogue: GELU + store (C layout m89) ----
  #pragma unroll
  for (int m = 0; m < 4; ++m) {
    #pragma unroll
    for (int n = 0; n < NF; ++n) {
      int rowb = wr * 64 + m * 16 + ((lane >> 4) << 2);
      int col  = n0 + wc * 128 + n * 16 + (lane & 15);
      #pragma unroll
      for (int jj = 0; jj < 4; ++jj) {
        float xv = acc[m][n][jj];
        float y = fminf(fmaxf(xv, -8.f), 8.f);
        float u = 0.7978845608f * (y + 0.044715f * y * y * y);
        float t2 = __expf(-2.f * u);
        float g = __fdividef(y, 1.f + t2);
        actout[(size_t)(row0 + rowb + jj) * N + col] = f2bf(g);
      }
    }
  }
}

// GEMM2 (round-17 proven form): A = act bf16 via global_load_lds dbuf,
// B = w2 NT-dwordx4, counted vmcnt; writes bf16 partials to h2.
template<int K, int N>
__global__ __launch_bounds__(512, 2)
void moe_gemm2(const u16* __restrict__ Abf, const float* __restrict__ Bf,
               u16* __restrict__ outp)
{
  constexpr int BM = 256, BN = 256, BK = 64;
  constexpr int NB = N / BN;
  constexpr int NT = K / BK;
  constexpr int NF = 8;
  constexpr int ABYTES = BM * 128;
  __shared__ __align__(16) char lds[2 * ABYTES + BN * 128];  // 96 KB
  char* Bs = lds + 2 * ABYTES;

  const int d = blockIdx.y * NB + blockIdx.x;
  const int x = d & 7, j = d >> 3;
  const int e  = x * (NE / 8) + j / NB;
  const int n0 = (j % NB) * BN;
  const int row0 = e * PER_E;
  const int tid  = threadIdx.x;
  const int lane = tid & 63, wid = tid >> 6;
  const int wr   = wid >> 1, wc = wid & 1;

  const u16*   Arow = Abf + (size_t)row0 * K;
  const float* Bsrc = Bf + (size_t)e * K * N + n0;
  const int nq = (tid & 63) * 4;
  const int kg = tid >> 6;

  auto stageA = [&](int buf, int k0) {
    char* dst = lds + buf * ABYTES;
    #pragma unroll
    for (int i = 0; i < 4; ++i) {
      int c = i * 512 + tid;
      int r = c >> 3, kc = c & 7;
      int kswz = kc ^ (r & 7);
      __builtin_amdgcn_global_load_lds(
          (const void*)(Arow + (size_t)r * K + k0 + kswz * 8),
          (void*)(dst + c * 16), 16, 0, 0);
    }
  };
  auto loadB = [&](f4* br4, int k0) {
    #pragma unroll
    for (int jj = 0; jj < 8; ++jj)
      br4[jj] = __builtin_nontemporal_load(
          (const f4*)(Bsrc + (size_t)(k0 + kg * 8 + jj) * N + nq));
  };
  auto writeB = [&](const f4* br4) {
    #pragma unroll
    for (int i = 0; i < 4; ++i) {
      int n = nq + i;
      u32 q[4];
      #pragma unroll
      for (int jj = 0; jj < 4; ++jj)
        q[jj] = pk2(br4[2 * jj][i], br4[2 * jj + 1][i]);
      *(uint4*)(Bs + n * 128 + ((kg * 16) ^ ((n & 7) << 4))) = *(uint4*)q;
    }
  };

  f4 acc[4][NF] = {};
  f4 breg[8];

  loadB(breg, 0); SB0;
  stageA(0, 0);
  asm volatile("s_waitcnt vmcnt(4)" ::: "memory"); SB0;
  writeB(breg);
  asm volatile("s_waitcnt lgkmcnt(0)" ::: "memory"); SB0;
  __builtin_amdgcn_s_barrier(); SB0;

  int cur = 0;
  for (int t = 0; t < NT; ++t) {
    const char* As = lds + cur * ABYTES;
    if (t + 1 < NT) {
      loadB(breg, (t + 1) * BK); SB0;
      stageA(cur ^ 1, (t + 1) * BK);
      asm volatile("s_waitcnt vmcnt(12)" ::: "memory");
    } else {
      asm volatile("s_waitcnt vmcnt(0)" ::: "memory");
    }
    SB0;
    __builtin_amdgcn_s_setprio(1);
    #pragma unroll
    for (int kk = 0; kk < 2; ++kk) {
      int kByte = kk * 64 + ((lane >> 4) << 4);
      bh8 a[4], b[NF];
      #pragma unroll
      for (int m = 0; m < 4; ++m) {
        int r = wr * 64 + m * 16 + (lane & 15);
        a[m] = *(const bh8*)(As + r * 128 + (kByte ^ ((r & 7) << 4)));
      }
      #pragma unroll
      for (int n = 0; n < NF; ++n) {
        int r = wc * 128 + n * 16 + (lane & 15);
        b[n] = *(const bh8*)(Bs + r * 128 + (kByte ^ ((r & 7) << 4)));
      }
      #pragma unroll
      for (int m = 0; m < 4; ++m)
        #pragma unroll
        for (int n = 0; n < NF; ++n)
          acc[m][n] = __builtin_amdgcn_mfma_f32_16x16x32_bf16(a[m], b[n], acc[m][n], 0, 0, 0);
    }
    __builtin_amdgcn_s_setprio(0);
    __builtin_amdgcn_s_barrier(); SB0;
    if (t + 1 < NT) {
      asm volatile("s_waitcnt vmcnt(4)" ::: "memory"); SB0;
      writeB(breg);
      asm volatile("s_waitcnt lgkmcnt(0)" ::: "memory"); SB0;
      __builtin_amdgcn_s_barrier(); SB0;
      cur ^= 1;
    }
  }

  #pragma unroll
  for (int m = 0; m < 4; ++m) {
    #pragma unroll
    for (int n = 0; n < NF; ++n) {
      int rowb = wr * 64 + m * 16 + ((lane >> 4) << 2);
      int col  = n0 + wc * 128 + n * 16 + (lane & 15);
      #pragma unroll
      for (int jj = 0; jj < 4; ++jj)
        outp[(size_t)(row0 + rowb + jj) * N + col] = f2bf(acc[m][n][jj]);
    }
  }
}

// out[t][:] = h2[sidx[2t]][:] + h2[sidx[2t+1]][:]  (h2 bf16 single-read -> NT;
// out f32 single-write -> NT)
__global__ void k_reduce(const u16* __restrict__ h2, const int* __restrict__ sidx,
                         float* __restrict__ out) {
  for (int i = blockIdx.x * 256 + threadIdx.x; i < NTOK * (HD / 4);
       i += 2048 * 256) {
    int t = i >> 8, c = i & 255;
    const u16* r0 = h2 + (size_t)sidx[2 * t] * HD + c * 4;
    const u16* r1 = h2 + (size_t)sidx[2 * t + 1] * HD + c * 4;
    u32x2 v0 = __builtin_nontemporal_load((const u32x2*)r0);
    u32x2 v1 = __builtin_nontemporal_load((const u32x2*)r1);
    u16 a0[4], a1[4];
    *(u32x2*)a0 = v0;
    *(u32x2*)a1 = v1;
    f4 s;
    #pragma unroll
    for (int jj = 0; jj < 4; ++jj) s[jj] = bf2f(a0[jj]) + bf2f(a1[jj]);
    __builtin_nontemporal_store(s, (f4*)(out + (size_t)t * HD + c * 4));
  }
}

extern "C" void kernel_launch(void* const* d_in, const int* in_sizes, int n_in,
                              void* d_out, int out_size, void* d_ws, size_t ws_size,
                              hipStream_t stream) {
  const float* inp  = (const float*)d_in[0];
  const float* w1   = (const float*)d_in[1];
  const float* w2   = (const float*)d_in[2];
  const int*   sidx = (const int*)d_in[3];
  float* out = (float*)d_out;

  char* ws   = (char*)d_ws;
  int*   s2t = (int*)ws;                                          // 64 KB
  u16*   act = (u16*)(ws + (1 << 20) + (32u << 20));              // 64 MB bf16 [MTOT][FFND]
  u16*   h2  = (u16*)(ws + (1 << 20) + (96u << 20));              // 32 MB bf16 [MTOT][HD]

  k_build_s2t<<<MTOT / 256, 256, 0, stream>>>(sidx, s2t);
  moe_gemm1<HD, FFND><<<dim3(FFND / 256, NE), 512, 0, stream>>>(inp, s2t, w1, act);
  moe_gemm2<FFND, HD><<<dim3(HD / 256, NE), 512, 0, stream>>>(act, w2, h2);
  k_reduce<<<2048, 256, 0, stream>>>(h2, sidx, out);
}